// Round 16
// baseline (2671.922 us; speedup 1.0000x reference)
//
#include <hip/hip_runtime.h>
#include <hip/hip_fp16.h>

// Many2OneRNN: B=64, S=4096, I=256, H=256, O=128
// Fused heterogeneous kernel, chunked over time (T_C=1024, 4 chunks):
//   blocks 0..63   : recurrence for chunk c (1 block/chain, 512 thr, 8 waves)
//   blocks 64..    : xp GEMM for chunk c+1  (64 t-rows/block, MFMA f16)
// R16 = R15 (MFMA matvec, broadcast-B) with the accumulator chain SPLIT:
//   4 independent depth-4 MFMA chains per wave (even/odd kt x 2 tiles)
//   instead of 2 depth-8 chains — R15's counters showed ~17 cyc/MFMA
//   dependent-issue stalls (MfmaUtil 34% on active CUs for 32 MFMA/step).
//   Merge = 8 v_add_f32.  Everything else unchanged from R15 (refcheck'd).
// rnn per wave/step: 8 broadcast ds_read_b128, 16 MFMA in 4 indep chains,
//   ~90 VALU (8 tanh etc), 2 masked ds_write_b64, 1 raw barrier (lgkmcnt).
// xp[b][h][t] f16 with BOTH biases folded (Wax_b + Waa_b).
// Phase 3 (out = sigmoid(Wya*a + Wya_b)) folded into the last rnn launch.

typedef _Float16 f16x8 __attribute__((ext_vector_type(8)));
typedef _Float16 f16x4 __attribute__((ext_vector_type(4)));
typedef float    f32x4 __attribute__((ext_vector_type(4)));

__global__ __launch_bounds__(512)
__attribute__((amdgpu_waves_per_eu(2, 2)))
void k_fused(
    const float* __restrict__ x, const float* __restrict__ Ww,
    const float* __restrict__ Wb, const float* __restrict__ Waa,
    const float* __restrict__ Wab, const float* __restrict__ Wya,
    const float* __restrict__ Wyb, float* __restrict__ out,
    _Float16* __restrict__ xp0, _Float16* __restrict__ xp1,
    unsigned short* __restrict__ a_state,
    int c_rnn, int c_xp, int do_rnn, int do_xp, int is_last,
    int T_C, int logT)
{
    // LDS: xp path uses As (33.8 KB); rnn path uses aB (1 KB) + afin (1 KB).
    __shared__ __align__(16) _Float16 As[64 * 264];
    __shared__ __align__(16) _Float16 aB[2][264];   // a-vector, dbuf
    __shared__ float afin[256];

    const int tid  = threadIdx.x;
    const int lane = tid & 63;

    if (blockIdx.x < 64) {
        // ================= RNN path: MFMA matvec, 1 chain =================
        if (!do_rnn) return;
        const _Float16* xp = (c_rnn & 1) ? xp1 : xp0;
        const int w   = tid >> 6;     // 0..7 : rows w*32..+32
        const int l15 = lane & 15;
        const int g   = lane >> 4;    // 0..3
        const int b   = blockIdx.x;
        const bool wl = (l15 == 0);   // writer lanes

        // --- A-frags: Waa rows (layout verified k_xp/R8/R15)
        f16x8 wa[2][8];
#pragma unroll
        for (int t = 0; t < 2; ++t) {
            const float* wrow = Waa + (size_t)(w * 32 + t * 16 + l15) * 256 + g * 8;
#pragma unroll
            for (int kt = 0; kt < 8; ++kt) {
                const float4* wp = (const float4*)(wrow + kt * 32);
                float4 v0 = wp[0], v1 = wp[1];
                f16x8 f;
                f[0] = (_Float16)v0.x; f[1] = (_Float16)v0.y;
                f[2] = (_Float16)v0.z; f[3] = (_Float16)v0.w;
                f[4] = (_Float16)v1.x; f[5] = (_Float16)v1.y;
                f[6] = (_Float16)v1.z; f[7] = (_Float16)v1.w;
                wa[t][kt] = f;
            }
        }

        // --- init a buffer 0
        if (tid < 256) {
            unsigned short v = 0;
            if (c_rnn != 0) v = a_state[b * 256 + tid];
            aB[0][tid] = __builtin_bit_cast(_Float16, v);
        }
        __syncthreads();

        // --- xp streams: 8 rows/lane (2 tiles x 4 C-rows), f16x8 per oct.
        const _Float16* xph[8];
#pragma unroll
        for (int s = 0; s < 8; ++s) {
            const int row = w * 32 + (s >> 2) * 16 + g * 4 + (s & 3);
            xph[s] = xp + ((size_t)(b * 256 + row)) * T_C;
        }
        f16x8 xq[8], xn[8];
#pragma unroll
        for (int s = 0; s < 8; ++s) xq[s] = *(const f16x8*)(xph[s]);

        const int row0 = w * 32 + g * 4;        // tile-0 first row (wl lanes)
        const int row1 = row0 + 16;             // tile-1 first row
        const _Float16* bp0 = &aB[0][g * 8];
        const _Float16* bp1 = &aB[1][g * 8];

#define RNN_STEP(P, J, FIN)                                                  \
    {                                                                        \
        const _Float16* bp = (P) ? bp1 : bp0;                                \
        f32x4 c0a = {0.f, 0.f, 0.f, 0.f}, c0b = c0a;                         \
        f32x4 c1a = c0a, c1b = c0a;                                          \
        _Pragma("unroll")                                                    \
        for (int k2 = 0; k2 < 4; ++k2) {                                     \
            f16x8 bf0 = *(const f16x8*)(bp + (2 * k2) * 32);                 \
            f16x8 bf1 = *(const f16x8*)(bp + (2 * k2 + 1) * 32);             \
            c0a = __builtin_amdgcn_mfma_f32_16x16x32_f16(wa[0][2 * k2],     bf0, c0a, 0, 0, 0); \
            c1a = __builtin_amdgcn_mfma_f32_16x16x32_f16(wa[1][2 * k2],     bf0, c1a, 0, 0, 0); \
            c0b = __builtin_amdgcn_mfma_f32_16x16x32_f16(wa[0][2 * k2 + 1], bf1, c0b, 0, 0, 0); \
            c1b = __builtin_amdgcn_mfma_f32_16x16x32_f16(wa[1][2 * k2 + 1], bf1, c1b, 0, 0, 0); \
        }                                                                    \
        f16x4 o0, o1;                                                        \
        _Pragma("unroll")                                                    \
        for (int r = 0; r < 4; ++r) {                                        \
            float z0 = (c0a[r] + c0b[r]) + (float)xq[r][(J)];                \
            float e0 = __expf(2.f * z0);                                     \
            o0[r] = (_Float16)fmaf(-2.f, __builtin_amdgcn_rcpf(e0 + 1.f), 1.f); \
            float z1 = (c1a[r] + c1b[r]) + (float)xq[4 + r][(J)];            \
            float e1 = __expf(2.f * z1);                                     \
            o1[r] = (_Float16)fmaf(-2.f, __builtin_amdgcn_rcpf(e1 + 1.f), 1.f); \
        }                                                                    \
        if (wl) {                                                            \
            *(f16x4*)&aB[(P) ^ 1][row0] = o0;                                \
            *(f16x4*)&aB[(P) ^ 1][row1] = o1;                                \
            if (FIN) {                                                       \
                _Pragma("unroll")                                            \
                for (int r = 0; r < 4; ++r) {                                \
                    afin[row0 + r] = (float)o0[r];                           \
                    afin[row1 + r] = (float)o1[r];                           \
                    a_state[b * 256 + row0 + r] =                            \
                        __builtin_bit_cast(unsigned short, o0[r]);           \
                    a_state[b * 256 + row1 + r] =                            \
                        __builtin_bit_cast(unsigned short, o1[r]);           \
                }                                                            \
            }                                                                \
        }                                                                    \
        asm volatile("s_waitcnt lgkmcnt(0)" ::: "memory");                   \
        __builtin_amdgcn_s_barrier();                                        \
        asm volatile("" ::: "memory");                                       \
    }

        for (int tb = 0; tb + 8 < T_C; tb += 8) {
#pragma unroll
            for (int s = 0; s < 8; ++s) xn[s] = *(const f16x8*)(xph[s] + tb + 8);
            RNN_STEP(0, 0, false) RNN_STEP(1, 1, false)
            RNN_STEP(0, 2, false) RNN_STEP(1, 3, false)
            RNN_STEP(0, 4, false) RNN_STEP(1, 5, false)
            RNN_STEP(0, 6, false) RNN_STEP(1, 7, false)
#pragma unroll
            for (int s = 0; s < 8; ++s) xq[s] = xn[s];
        }
        RNN_STEP(0, 0, false) RNN_STEP(1, 1, false)
        RNN_STEP(0, 2, false) RNN_STEP(1, 3, false)
        RNN_STEP(0, 4, false) RNN_STEP(1, 5, false)
        RNN_STEP(0, 6, false) RNN_STEP(1, 7, true)
#undef RNN_STEP

        // --- Phase 3: out = sigmoid(Wya * a_last + Wyb), last chunk only
        if (is_last) {
            const int o  = tid >> 2;   // 0..127
            const int k4 = tid & 3;    // 4-way K split
            const float4* wp = (const float4*)(Wya + (size_t)o * 256 + k4 * 64);
            const float4* ap = (const float4*)(afin + k4 * 64);
            float s = 0.f;
#pragma unroll
            for (int i = 0; i < 16; ++i) {
                float4 wv4 = wp[i];
                float4 a4  = ap[i];
                s += wv4.x * a4.x + wv4.y * a4.y + wv4.z * a4.z + wv4.w * a4.w;
            }
            s += __shfl_xor(s, 1);
            s += __shfl_xor(s, 2);
            if (k4 == 0)
                out[b * 128 + o] = __builtin_amdgcn_rcpf(1.f + __expf(-(s + Wyb[o])));
        }
    } else {
        // ================= XP path (chunk c_xp, 64 t-rows/block) =========
        if (!do_xp) return;
        _Float16* xp = (c_xp & 1) ? xp1 : xp0;
        const int bxp = blockIdx.x - 64;
        const int wv  = tid >> 6;    // 0..7
        const int l15 = lane & 15;
        const int lk  = lane >> 4;   // 0..3
        const int n0  = wv * 32;

        // B fragments (Wax_w rows = N dim, K contiguous) in registers
        f16x8 bfr[2][8];
#pragma unroll
        for (int nt = 0; nt < 2; ++nt) {
            const float* wrow = Ww + (size_t)(n0 + nt * 16 + l15) * 256;
#pragma unroll
            for (int kt = 0; kt < 8; ++kt) {
                const float4* wp = (const float4*)(wrow + kt * 32 + lk * 8);
                float4 v0 = wp[0], v1 = wp[1];
                f16x8 f;
                f[0] = (_Float16)v0.x; f[1] = (_Float16)v0.y;
                f[2] = (_Float16)v0.z; f[3] = (_Float16)v0.w;
                f[4] = (_Float16)v1.x; f[5] = (_Float16)v1.y;
                f[6] = (_Float16)v1.z; f[7] = (_Float16)v1.w;
                bfr[nt][kt] = f;
            }
        }
        // BOTH biases folded into xp (rnn adds none)
        const float bias0 = Wb[n0 + l15]      + Wab[n0 + l15];
        const float bias1 = Wb[n0 + 16 + l15] + Wab[n0 + 16 + l15];

        // stage A tile (64 rows x 256 K) f32 -> f16 LDS
        {
            const int arow = tid >> 3;           // 0..63
            const int acol = (tid & 7) * 32;     // 0..224
            const int r    = bxp * 64 + arow;
            const int bb   = r >> logT;
            const int tl   = r & (T_C - 1);
            const float4* s4 = (const float4*)(x + ((size_t)(bb * 4096 + c_xp * T_C + tl) << 8) + acol);
            _Float16* d = As + arow * 264 + acol;
#pragma unroll
            for (int q = 0; q < 4; ++q) {
                float4 v0 = s4[2 * q], v1 = s4[2 * q + 1];
                f16x8 p;
                p[0] = (_Float16)v0.x; p[1] = (_Float16)v0.y;
                p[2] = (_Float16)v0.z; p[3] = (_Float16)v0.w;
                p[4] = (_Float16)v1.x; p[5] = (_Float16)v1.y;
                p[6] = (_Float16)v1.z; p[7] = (_Float16)v1.w;
                *(f16x8*)(d + q * 8) = p;
            }
        }
        __syncthreads();

        f32x4 acc[4][2] = {};
#pragma unroll
        for (int kt = 0; kt < 8; ++kt) {
#pragma unroll
            for (int mt = 0; mt < 4; ++mt) {
                f16x8 af = *(const f16x8*)(As + (mt * 16 + l15) * 264 + kt * 32 + lk * 8);
                acc[mt][0] = __builtin_amdgcn_mfma_f32_16x16x32_f16(af, bfr[0][kt], acc[mt][0], 0, 0, 0);
                acc[mt][1] = __builtin_amdgcn_mfma_f32_16x16x32_f16(af, bfr[1][kt], acc[mt][1], 0, 0, 0);
            }
        }

        // store xp3[b][h][t]: 4 t-contiguous halves per 8B store
        const int base = bxp * 64;
#pragma unroll
        for (int mt = 0; mt < 4; ++mt) {
            const int rr  = base + mt * 16 + lk * 4;
            const int bb2 = rr >> logT;
            const int tt  = rr & (T_C - 1);
#pragma unroll
            for (int nt = 0; nt < 2; ++nt) {
                const int   h    = n0 + nt * 16 + l15;
                const float bias = (nt == 0) ? bias0 : bias1;
                f16x4 pk;
#pragma unroll
                for (int r2 = 0; r2 < 4; ++r2) pk[r2] = (_Float16)(acc[mt][nt][r2] + bias);
                *(f16x4*)(xp + ((size_t)(bb2 * 256 + h)) * T_C + tt) = pk;
            }
        }
    }
}

// ---------------------------------------------------------------------------
extern "C" void kernel_launch(void* const* d_in, const int* in_sizes, int n_in,
                              void* d_out, int out_size, void* d_ws, size_t ws_size,
                              hipStream_t stream)
{
    (void)in_sizes; (void)n_in; (void)out_size;
    const float* x    = (const float*)d_in[0];
    const float* Waxw = (const float*)d_in[1];
    const float* Waxb = (const float*)d_in[2];
    const float* Waaw = (const float*)d_in[3];
    const float* Waab = (const float*)d_in[4];
    const float* Wyaw = (const float*)d_in[5];
    const float* Wyab = (const float*)d_in[6];
    float* out = (float*)d_out;

    // chunk size: T_C=1024 (4 chunks) for xp/rnn overlap; shrink to fit ws
    // (needs 2 xp chunk buffers + 32KB state).
    int T_C = 1024, logT = 10;
    while (T_C > 128 && (size_t)2 * 64 * T_C * 256 * 2 + 32768 > ws_size) { T_C >>= 1; --logT; }

    _Float16* xp0 = (_Float16*)d_ws;
    _Float16* xp1 = xp0 + (size_t)64 * T_C * 256;
    unsigned short* a_state = (unsigned short*)(xp1 + (size_t)64 * T_C * 256);

    const int nc  = 4096 / T_C;
    const int nxp = T_C;   // xp blocks per chunk (64 t-rows each)
    for (int i = 0; i <= nc; ++i) {
        // launch i: rnn on chunk i-1 (if any) overlapped with xp on chunk i
        k_fused<<<dim3(64 + nxp), dim3(512), 0, stream>>>(
            x, Waxw, Waxb, Waaw, Waab, Wyaw, Wyab, out, xp0, xp1, a_state,
            i - 1, i, i >= 1 ? 1 : 0, i < nc ? 1 : 0, i == nc ? 1 : 0,
            T_C, logT);
    }
}

// Round 17
// 1909.280 us; speedup vs baseline: 1.3994x; 1.3994x over previous
//
#include <hip/hip_runtime.h>
#include <hip/hip_fp16.h>

// Many2OneRNN: B=64, S=4096, I=256, H=256, O=128
// FINAL (= R14, best measured 1916 us): fused heterogeneous kernel,
// chunked over time (T_C=1024, 4 chunks):
//   blocks 0..63   : recurrence for chunk c (1 block/chain, 512 thr, 8 waves)
//   blocks 64..    : xp GEMM for chunk c+1  (64 t-rows/block, MFMA f16)
// xp double-buffered in d_ws so launch i overlaps rnn(i-1) with xp(i).
// Recurrence decomposition: 512 threads / 8 rows per thread (redundancy 2).
//   Per thread/step: 2 ds_read_b128 (broadcast), 64 fdot2, 15-DPP period-8
//   rotate-reduce, 5-op tanh, predicated ds_write_b16 (k<8), 1 raw barrier
//   (lgkmcnt only — xp prefetch stays in flight).
// Structural floor (measured across R9-R16): step = 1130 cyc = 512 MAC-issue
//   (dot2 is half-rate; invariant across dot2/pk_fma/fma_f32/asm encodings)
//   + ~620 serial/glue (barrier, LDS latency, dep chain). MFMA matvec
//   (R15/16) and chain-stacking (R12) both regress; xp is fully hidden.
// Phase 3 (out = sigmoid(Wya*a + Wya_b)) folded into the last rnn launch.

typedef _Float16 f16x8 __attribute__((ext_vector_type(8)));
typedef _Float16 f16x4 __attribute__((ext_vector_type(4)));
typedef _Float16 f16x2 __attribute__((ext_vector_type(2)));
typedef float    f32x4 __attribute__((ext_vector_type(4)));

#define FDOT2(a, b, c) __builtin_amdgcn_fdot2((a), (b), (c), false)

// row_ror:D within 16 lanes: dst lane i gets src lane (i-D)&15
template <int D>
__device__ __forceinline__ float rorf(float v) {
    return __builtin_bit_cast(float,
        __builtin_amdgcn_update_dpp(0, __builtin_bit_cast(int, v),
                                    0x120 + D, 0xF, 0xF, true));
}

__global__ __launch_bounds__(512)
__attribute__((amdgpu_waves_per_eu(2, 2)))
void k_fused(
    const float* __restrict__ x, const float* __restrict__ Ww,
    const float* __restrict__ Wb, const float* __restrict__ Waa,
    const float* __restrict__ Wab, const float* __restrict__ Wya,
    const float* __restrict__ Wyb, float* __restrict__ out,
    _Float16* __restrict__ xp0, _Float16* __restrict__ xp1,
    unsigned short* __restrict__ a_state,
    int c_rnn, int c_xp, int do_rnn, int do_xp, int is_last,
    int T_C, int logT)
{
    // LDS: xp path uses As (33.8 KB); rnn path uses aL/afin (2.5 KB).
    __shared__ __align__(16) _Float16 As[64 * 264];
    __shared__ __align__(16) _Float16 aL[2][16][24];
    __shared__ float afin[256];

    const int tid  = threadIdx.x;
    const int lane = tid & 63;

    if (blockIdx.x < 64) {
        // ================= RNN path: 8 rows/thread =================
        if (!do_rnn) return;
        const _Float16* xp = (c_rnn & 1) ? xp1 : xp0;
        const int w     = tid >> 6;      // 0..7
        const int k     = lane & 15;     // K-slice [k*16, k*16+16)
        const int g     = lane >> 4;     // 0..3
        const int rbase = w * 32 + g * 8;
        const int myrow = rbase + (k & 7);
        const int b     = blockIdx.x;
        const bool wlane = (k & 8) == 0;   // 8 writer lanes cover the 8 rows

        // weights: slot i -> row rbase+((k+i)&7), K-contiguous f16x2 (64 VGPR)
        f16x2 wr[8][8];
#pragma unroll
        for (int i = 0; i < 8; ++i) {
            const float4* wp = (const float4*)(Waa + (size_t)(rbase + ((k + i) & 7)) * 256 + k * 16);
#pragma unroll
            for (int q = 0; q < 4; ++q) {
                float4 v = wp[q];
                f16x2 t0; t0[0] = (_Float16)v.x; t0[1] = (_Float16)v.y;
                f16x2 t1; t1[0] = (_Float16)v.z; t1[1] = (_Float16)v.w;
                wr[i][2 * q]     = t0;
                wr[i][2 * q + 1] = t1;
            }
        }
        const float bias = Wab[myrow];

        if (tid < 256) {
            unsigned short v = 0;
            if (c_rnn != 0) v = a_state[b * 256 + tid];
            aL[0][tid >> 4][tid & 15] = __builtin_bit_cast(_Float16, v);
        }
        __syncthreads();

        const _Float16* xph = xp + ((size_t)(b * 256 + myrow)) * T_C;
        f16x8 xq = *(const f16x8*)(xph);
        float bx[8];
#pragma unroll
        for (int j = 0; j < 8; ++j) bx[j] = bias + (float)xq[j];

        const _Float16* rp0 = &aL[0][k][0];
        const _Float16* rp1 = &aL[1][k][0];
        _Float16* wq0 = &aL[1][myrow >> 4][myrow & 15];  // wlane only
        _Float16* wq1 = &aL[0][myrow >> 4][myrow & 15];

#define RNN_STEP(J, FIN)                                                     \
    {                                                                        \
        const _Float16* rp = ((J) & 1) ? rp1 : rp0;                          \
        uint4 r0 = *(const uint4*)(rp);                                      \
        uint4 r1 = *(const uint4*)(rp + 8);                                  \
        f16x2 a2[8];                                                         \
        a2[0] = __builtin_bit_cast(f16x2, r0.x);                             \
        a2[1] = __builtin_bit_cast(f16x2, r0.y);                             \
        a2[2] = __builtin_bit_cast(f16x2, r0.z);                             \
        a2[3] = __builtin_bit_cast(f16x2, r0.w);                             \
        a2[4] = __builtin_bit_cast(f16x2, r1.x);                             \
        a2[5] = __builtin_bit_cast(f16x2, r1.y);                             \
        a2[6] = __builtin_bit_cast(f16x2, r1.z);                             \
        a2[7] = __builtin_bit_cast(f16x2, r1.w);                             \
        float s0 = 0.f, s1 = 0.f, s2 = 0.f, s3 = 0.f;                        \
        float s4 = 0.f, s5 = 0.f, s6 = 0.f, s7 = 0.f;                        \
        _Pragma("unroll")                                                    \
        for (int q = 0; q < 8; ++q) {                                        \
            s0 = FDOT2(wr[0][q], a2[q], s0);                                 \
            s1 = FDOT2(wr[1][q], a2[q], s1);                                 \
            s2 = FDOT2(wr[2][q], a2[q], s2);                                 \
            s3 = FDOT2(wr[3][q], a2[q], s3);                                 \
            s4 = FDOT2(wr[4][q], a2[q], s4);                                 \
            s5 = FDOT2(wr[5][q], a2[q], s5);                                 \
            s6 = FDOT2(wr[6][q], a2[q], s6);                                 \
            s7 = FDOT2(wr[7][q], a2[q], s7);                                 \
        }                                                                    \
        /* period-8 rotate-reduce over 16 K-lanes:                           \
           total(row k&7) = sum_c ror_c( p_c + ror4(p_{c+4}) ),              \
           p_i = s_i + ror8(s_i) */                                          \
        float p0 = s0 + rorf<8>(s0);                                         \
        float p1 = s1 + rorf<8>(s1);                                         \
        float p2 = s2 + rorf<8>(s2);                                         \
        float p3 = s3 + rorf<8>(s3);                                         \
        float p4 = s4 + rorf<8>(s4);                                         \
        float p5 = s5 + rorf<8>(s5);                                         \
        float p6 = s6 + rorf<8>(s6);                                         \
        float p7 = s7 + rorf<8>(s7);                                         \
        float q0 = p0 + rorf<4>(p4);                                         \
        float q1 = p1 + rorf<4>(p5);                                         \
        float q2 = p2 + rorf<4>(p6);                                         \
        float q3 = p3 + rorf<4>(p7);                                         \
        float acc = (q0 + rorf<1>(q1)) + (rorf<2>(q2) + rorf<3>(q3));        \
        float z  = bx[(J)] + acc;                                            \
        float e2 = __expf(2.f * z);                                          \
        float a  = fmaf(-2.f, __builtin_amdgcn_rcpf(e2 + 1.f), 1.f);         \
        _Float16 ah = (_Float16)a;                                           \
        if (wlane) *(((J) & 1) ? wq1 : wq0) = ah;                            \
        if (FIN) {                                                           \
            afin[myrow] = a;                                                 \
            a_state[b * 256 + myrow] = __builtin_bit_cast(unsigned short, ah);\
        }                                                                    \
        asm volatile("s_waitcnt lgkmcnt(0)" ::: "memory");                   \
        __builtin_amdgcn_s_barrier();                                        \
        asm volatile("" ::: "memory");                                       \
    }

        for (int tb = 0; tb + 8 < T_C; tb += 8) {
            f16x8 xn = *(const f16x8*)(xph + tb + 8);
            RNN_STEP(0, false) RNN_STEP(1, false) RNN_STEP(2, false) RNN_STEP(3, false)
            RNN_STEP(4, false) RNN_STEP(5, false) RNN_STEP(6, false) RNN_STEP(7, false)
#pragma unroll
            for (int j = 0; j < 8; ++j) bx[j] = bias + (float)xn[j];
        }
        RNN_STEP(0, false) RNN_STEP(1, false) RNN_STEP(2, false) RNN_STEP(3, false)
        RNN_STEP(4, false) RNN_STEP(5, false) RNN_STEP(6, false) RNN_STEP(7, true)
#undef RNN_STEP

        // --- Phase 3: out = sigmoid(Wya * a_last + Wyb), last chunk only
        if (is_last) {
            const int o  = tid >> 2;   // 0..127
            const int k4 = tid & 3;    // 4-way K split
            const float4* wp = (const float4*)(Wya + (size_t)o * 256 + k4 * 64);
            const float4* ap = (const float4*)(afin + k4 * 64);
            float s = 0.f;
#pragma unroll
            for (int i = 0; i < 16; ++i) {
                float4 wv4 = wp[i];
                float4 a4  = ap[i];
                s += wv4.x * a4.x + wv4.y * a4.y + wv4.z * a4.z + wv4.w * a4.w;
            }
            s += __shfl_xor(s, 1);
            s += __shfl_xor(s, 2);
            if (k4 == 0)
                out[b * 128 + o] = __builtin_amdgcn_rcpf(1.f + __expf(-(s + Wyb[o])));
        }
    } else {
        // ================= XP path (chunk c_xp, 64 t-rows/block) =========
        if (!do_xp) return;
        _Float16* xp = (c_xp & 1) ? xp1 : xp0;
        const int bxp = blockIdx.x - 64;
        const int wv  = tid >> 6;    // 0..7
        const int l15 = lane & 15;
        const int lk  = lane >> 4;   // 0..3
        const int n0  = wv * 32;

        // B fragments (Wax_w rows = N dim, K contiguous) in registers
        f16x8 bfr[2][8];
#pragma unroll
        for (int nt = 0; nt < 2; ++nt) {
            const float* wrow = Ww + (size_t)(n0 + nt * 16 + l15) * 256;
#pragma unroll
            for (int kt = 0; kt < 8; ++kt) {
                const float4* wp = (const float4*)(wrow + kt * 32 + lk * 8);
                float4 v0 = wp[0], v1 = wp[1];
                f16x8 f;
                f[0] = (_Float16)v0.x; f[1] = (_Float16)v0.y;
                f[2] = (_Float16)v0.z; f[3] = (_Float16)v0.w;
                f[4] = (_Float16)v1.x; f[5] = (_Float16)v1.y;
                f[6] = (_Float16)v1.z; f[7] = (_Float16)v1.w;
                bfr[nt][kt] = f;
            }
        }
        const float bias0 = Wb[n0 + l15];
        const float bias1 = Wb[n0 + 16 + l15];

        // stage A tile (64 rows x 256 K) f32 -> f16 LDS
        {
            const int arow = tid >> 3;           // 0..63
            const int acol = (tid & 7) * 32;     // 0..224
            const int r    = bxp * 64 + arow;
            const int bb   = r >> logT;
            const int tl   = r & (T_C - 1);
            const float4* s4 = (const float4*)(x + ((size_t)(bb * 4096 + c_xp * T_C + tl) << 8) + acol);
            _Float16* d = As + arow * 264 + acol;
#pragma unroll
            for (int q = 0; q < 4; ++q) {
                float4 v0 = s4[2 * q], v1 = s4[2 * q + 1];
                f16x8 p;
                p[0] = (_Float16)v0.x; p[1] = (_Float16)v0.y;
                p[2] = (_Float16)v0.z; p[3] = (_Float16)v0.w;
                p[4] = (_Float16)v1.x; p[5] = (_Float16)v1.y;
                p[6] = (_Float16)v1.z; p[7] = (_Float16)v1.w;
                *(f16x8*)(d + q * 8) = p;
            }
        }
        __syncthreads();

        f32x4 acc[4][2] = {};
#pragma unroll
        for (int kt = 0; kt < 8; ++kt) {
#pragma unroll
            for (int mt = 0; mt < 4; ++mt) {
                f16x8 af = *(const f16x8*)(As + (mt * 16 + l15) * 264 + kt * 32 + lk * 8);
                acc[mt][0] = __builtin_amdgcn_mfma_f32_16x16x32_f16(af, bfr[0][kt], acc[mt][0], 0, 0, 0);
                acc[mt][1] = __builtin_amdgcn_mfma_f32_16x16x32_f16(af, bfr[1][kt], acc[mt][1], 0, 0, 0);
            }
        }

        // store xp3[b][h][t]: 4 t-contiguous halves per 8B store
        const int base = bxp * 64;
#pragma unroll
        for (int mt = 0; mt < 4; ++mt) {
            const int rr  = base + mt * 16 + lk * 4;
            const int bb2 = rr >> logT;
            const int tt  = rr & (T_C - 1);
#pragma unroll
            for (int nt = 0; nt < 2; ++nt) {
                const int   h    = n0 + nt * 16 + l15;
                const float bias = (nt == 0) ? bias0 : bias1;
                f16x4 pk;
#pragma unroll
                for (int r2 = 0; r2 < 4; ++r2) pk[r2] = (_Float16)(acc[mt][nt][r2] + bias);
                *(f16x4*)(xp + ((size_t)(bb2 * 256 + h)) * T_C + tt) = pk;
            }
        }
    }
}

// ---------------------------------------------------------------------------
extern "C" void kernel_launch(void* const* d_in, const int* in_sizes, int n_in,
                              void* d_out, int out_size, void* d_ws, size_t ws_size,
                              hipStream_t stream)
{
    (void)in_sizes; (void)n_in; (void)out_size;
    const float* x    = (const float*)d_in[0];
    const float* Waxw = (const float*)d_in[1];
    const float* Waxb = (const float*)d_in[2];
    const float* Waaw = (const float*)d_in[3];
    const float* Waab = (const float*)d_in[4];
    const float* Wyaw = (const float*)d_in[5];
    const float* Wyab = (const float*)d_in[6];
    float* out = (float*)d_out;

    // chunk size: T_C=1024 (4 chunks) for xp/rnn overlap; shrink to fit ws
    // (needs 2 xp chunk buffers + 32KB state).
    int T_C = 1024, logT = 10;
    while (T_C > 128 && (size_t)2 * 64 * T_C * 256 * 2 + 32768 > ws_size) { T_C >>= 1; --logT; }

    _Float16* xp0 = (_Float16*)d_ws;
    _Float16* xp1 = xp0 + (size_t)64 * T_C * 256;
    unsigned short* a_state = (unsigned short*)(xp1 + (size_t)64 * T_C * 256);

    const int nc  = 4096 / T_C;
    const int nxp = T_C;   // xp blocks per chunk (64 t-rows each)
    for (int i = 0; i <= nc; ++i) {
        // launch i: rnn on chunk i-1 (if any) overlapped with xp on chunk i
        k_fused<<<dim3(64 + nxp), dim3(512), 0, stream>>>(
            x, Waxw, Waxb, Waaw, Waab, Wyaw, Wyab, out, xp0, xp1, a_state,
            i - 1, i, i >= 1 ? 1 : 0, i < nc ? 1 : 0, i == nc ? 1 : 0,
            T_C, logT);
    }
}